// Round 8
// baseline (10466.744 us; speedup 1.0000x reference)
//
#include <hip/hip_runtime.h>
#include <math.h>

#define T_LEN 512
#define NB    32
#define EMB_  41
#define IN0_  42
#define HID_  800
#define G4_   3200
#define IN1_  1600
#define NU    20
#define NCH0  50    // layer-0 blocks per direction (16 units each)
#define NCH1  100   // layer-1 blocks per direction (8 units each)

typedef unsigned short u16;
typedef unsigned int   u32;
typedef unsigned long long u64;
typedef __attribute__((ext_vector_type(8))) short short8;
typedef __attribute__((ext_vector_type(4))) float f32x4;

__device__ __forceinline__ float bf2f(u16 v) {
    union { u32 u; float f; } c; c.u = ((u32)v) << 16; return c.f;
}
__device__ __forceinline__ u16 f2bf(float f) {
    union { float f; u32 u; } c; c.f = f;
    u32 r = (c.u + 0x7fffu + ((c.u >> 16) & 1u)) >> 16;
    return (u16)r;
}
__device__ __forceinline__ short cvt_hl(float v, int hl) {
    u16 hi = f2bf(v);
    return hl ? (short)f2bf(v - bf2f(hi)) : (short)hi;
}
__device__ __forceinline__ f32x4 mfma16(short8 a, short8 b, f32x4 c) {
    return __builtin_amdgcn_mfma_f32_16x16x32_bf16(a, b, c, 0, 0, 0);
}
__device__ __forceinline__ u64 aload(const u64* p) {
    return __hip_atomic_load(p, __ATOMIC_RELAXED, __HIP_MEMORY_SCOPE_AGENT);
}
__device__ __forceinline__ void astore(u64* p, u64 v) {
    __hip_atomic_store(p, v, __ATOMIC_RELAXED, __HIP_MEMORY_SCOPE_AGENT);
}
__device__ __forceinline__ int afload(const int* p) {
    return __hip_atomic_load(p, __ATOMIC_RELAXED, __HIP_MEMORY_SCOPE_AGENT);
}
__device__ __forceinline__ void afstore(int* p, int v) {
    __hip_atomic_store(p, v, __ATOMIC_RELAXED, __HIP_MEMORY_SCOPE_AGENT);
}

// ---------------- Layer 0: persistent, 2 x 50 blocks x 256 threads ----------------
// Block (d,ch): 16 hidden units. Wave w = gate g; hi/lo whh accumulated in-register
// (same MFMA accumulator), so no cross-wave LDS reduce. Input GEMM also MFMA:
// x (fp32 seq) split hi/lo bf16 B-frags; exact position feature stays as t*wpos.
__global__ __launch_bounds__(256, 1)
void lstm0_persist(const float* __restrict__ seq, const float* __restrict__ wih0,
                   const float* __restrict__ whh0, const float* __restrict__ bias,
                   u16* __restrict__ h0f, u16* __restrict__ hB, int* __restrict__ flags)
{
    __shared__ __align__(16) float part[2048];      // [g][nt][16][16] 8 KB
    __shared__ __align__(16) u16 stageB[25600];     // 51.2 KB h-slab stage
    __shared__ __align__(16) u16 xf[2][2048];       // x hi/lo B-frags (K=64 pad) 8 KB
    __shared__ u16 hpk[NB*16];                      // 1 KB
    const int tid = threadIdx.x;
    const int d = blockIdx.x / NCH0, ch = blockIdx.x % NCH0;
    const int w = tid >> 6, l = tid & 63;           // w = gate
    int* myflags = flags + d*NCH0*16;

    // whh0 -> hi/lo A-frags for gate w, 16 units (register-resident)
    short8 wreg[2][25];
    {
        const int m = l & 15, j = ch*16 + m;
        const float* base = whh0 + ((size_t)(d*G4_ + w*HID_ + j))*HID_ + (l>>4)*8;
#pragma unroll
        for (int kc = 0; kc < 25; ++kc) {
            float4 f0 = *(const float4*)(base + kc*32);
            float4 f1 = *(const float4*)(base + kc*32 + 4);
            float vv[8] = {f0.x,f0.y,f0.z,f0.w,f1.x,f1.y,f1.z,f1.w};
            short8 vh, vl;
#pragma unroll
            for (int e = 0; e < 8; ++e) {
                u16 hi = f2bf(vv[e]);
                vh[e] = (short)hi;
                vl[e] = (short)f2bf(vv[e] - bf2f(hi));
            }
            wreg[0][kc] = vh; wreg[1][kc] = vl;
        }
    }
    // w_ih0 (k<41) -> hi/lo A-frags, K padded to 64 (2 kc tiles)
    short8 wx[2][2];
    {
        const int m = l & 15, j = ch*16 + m;
#pragma unroll
        for (int kc2 = 0; kc2 < 2; ++kc2) {
            short8 vh, vl;
#pragma unroll
            for (int e = 0; e < 8; ++e) {
                int k = kc2*32 + (l>>4)*8 + e;
                float v = (k < EMB_) ? wih0[((size_t)(d*G4_ + w*HID_ + j))*IN0_ + k] : 0.f;
                u16 hi = f2bf(v);
                vh[e] = (short)hi;
                vl[e] = (short)f2bf(v - bf2f(hi));
            }
            wx[0][kc2] = vh; wx[1][kc2] = vl;
        }
    }
    const int jub = tid >> 5, b = tid & 31;         // update: 2 pairs (jub, jub+8) x b
    const int nt = b >> 4, n = b & 15;
    float biasr[2][4], wpos[2][4], creg[2] = {0.f, 0.f};
#pragma unroll
    for (int pi = 0; pi < 2; ++pi) {
        const int j = ch*16 + jub + pi*8;
#pragma unroll
        for (int g = 0; g < 4; ++g) {
            biasr[pi][g] = bias[d*G4_ + g*HID_ + j];
            wpos[pi][g]  = wih0[((size_t)(d*G4_ + g*HID_ + j))*IN0_ + EMB_];
        }
    }
    __syncthreads();

    for (int s = 0; s < T_LEN; ++s) {
        const int t = d ? (T_LEN-1-s) : s;
        const u64* hq64 = (const u64*)(hB + (size_t)((s&1)*2 + d)*25600);
        u64*      hnq  = (u64*)(hB + (size_t)(((s&1)^1)*2 + d)*25600);

        // pre-poll: build x hi/lo B-frags for this t (overlaps peers' flag propagation)
        {
            const int e0 = tid*8;
            const int kc2 = e0 >> 10, nt_ = (e0 >> 9) & 1, l_ = (e0 >> 3) & 63;
            const int kb = kc2*32 + (l_>>4)*8;
            const float* sp = seq + (size_t)t*(NB*EMB_) + (nt_*16 + (l_&15))*EMB_;
#pragma unroll
            for (int e = 0; e < 8; ++e) {
                int k = kb + e;
                float v = (k < EMB_) ? sp[k] : 0.f;
                u16 hi = f2bf(v);
                xf[0][e0+e] = hi;
                xf[1][e0+e] = f2bf(v - bf2f(hi));
            }
        }
        if (s > 0 && tid < NCH0)
            while (afload(myflags + tid*16) < s) __builtin_amdgcn_s_sleep(1);
        __syncthreads();

        {   // stage the 51.2 KB B-slab once per block
            u64 tmp[25];
#pragma unroll
            for (int q = 0; q < 25; ++q) tmp[q] = aload(hq64 + tid + q*256);
#pragma unroll
            for (int q = 0; q < 25; ++q) ((u64*)stageB)[tid + q*256] = tmp[q];
        }
        __syncthreads();

        f32x4 acc0 = {0.f,0.f,0.f,0.f}, acc1 = {0.f,0.f,0.f,0.f};
#pragma unroll 5
        for (int kc = 0; kc < 25; ++kc) {
            short8 b0 = *(const short8*)(stageB + kc*1024 + l*8);
            short8 b1 = *(const short8*)(stageB + kc*1024 + 512 + l*8);
            acc0 = mfma16(wreg[0][kc], b0, acc0);
            acc0 = mfma16(wreg[1][kc], b0, acc0);
            acc1 = mfma16(wreg[0][kc], b1, acc1);
            acc1 = mfma16(wreg[1][kc], b1, acc1);
        }
        // x-part: (wh+wl)(xh+xl) ~= wh*xh + wh*xl + wl*xh
#pragma unroll
        for (int kc2 = 0; kc2 < 2; ++kc2) {
            short8 xh0 = *(const short8*)(&xf[0][(kc2*2+0)*512] + l*8);
            short8 xl0 = *(const short8*)(&xf[1][(kc2*2+0)*512] + l*8);
            short8 xh1 = *(const short8*)(&xf[0][(kc2*2+1)*512] + l*8);
            short8 xl1 = *(const short8*)(&xf[1][(kc2*2+1)*512] + l*8);
            acc0 = mfma16(wx[0][kc2], xh0, acc0);
            acc0 = mfma16(wx[0][kc2], xl0, acc0);
            acc0 = mfma16(wx[1][kc2], xh0, acc0);
            acc1 = mfma16(wx[0][kc2], xh1, acc1);
            acc1 = mfma16(wx[0][kc2], xl1, acc1);
            acc1 = mfma16(wx[1][kc2], xh1, acc1);
        }
        {
            const int mrow = (l>>4)*4, nn = l & 15;
#pragma unroll
            for (int r = 0; r < 4; ++r) {
                part[((w*2 + 0)*16 + mrow + r)*16 + nn] = acc0[r];
                part[((w*2 + 1)*16 + mrow + r)*16 + nn] = acc1[r];
            }
        }
        __syncthreads();

        // update: 2 (unit,batch) pairs per thread; gates complete in part already
#pragma unroll
        for (int pi = 0; pi < 2; ++pi) {
            const int ju = jub + pi*8;
            float v[4];
#pragma unroll
            for (int g = 0; g < 4; ++g)
                v[g] = part[((g*2 + nt)*16 + ju)*16 + n] + biasr[pi][g] + (float)t * wpos[pi][g];
            float ig = 1.f/(1.f + expf(-v[0]));
            float fg = 1.f/(1.f + expf(-v[1]));
            float gg = tanhf(v[2]);
            float og = 1.f/(1.f + expf(-v[3]));
            creg[pi] = fg * creg[pi] + ig * gg;
            hpk[b*16 + ju] = f2bf(og * tanhf(creg[pi]));
        }
        __syncthreads();

        u64 pk = 0; int xoff = 0;
        if (tid < 128) {
            const int half = tid & 1;
            const int pn   = (tid >> 1) & 15;
            const int ng   = (tid >> 5) & 1;
            const int pnt  = (tid >> 6) & 1;
            const int bb   = pnt*16 + pn;
            const int jbase = ng*8 + half*4;
            const u16* hp = &hpk[bb*16 + jbase];
            pk = (u64)hp[0] | ((u64)hp[1]<<16) | ((u64)hp[2]<<32) | ((u64)hp[3]<<48);
            const int lst = (((ch&1)*2 + ng) << 4) | pn;
            const int kc  = ch >> 1;
            astore(hnq + (kc*2 + pnt)*128 + lst*2 + half, pk);        // next-step h
            xoff = ((d*25 + kc)*2 + pnt)*128 + lst*2 + half;
        }
        __syncthreads();                       // drains vmcnt: hB stores at coherence point
        if (tid == 0) afstore(myflags + ch*16, s+1);
        if (tid < 128)                         // cross-dispatch store AFTER the flag
            ((u64*)(h0f + (size_t)t*51200))[xoff] = pk;
    }
}

// distributed logit owner: block ch computes 7 of the 640 (b,u) outputs for tprev
// from stageB (which holds h1[tprev]); plain store, zero contention.
__device__ __forceinline__ void logit_from_stage(const u16* __restrict__ stageB,
        const float* __restrict__ lin_w, float* __restrict__ logits,
        int d, int ch, int tprev, int tid)
{
    const int ol = tid >> 5, ln = tid & 31;
    if (ol >= 7) return;
    const int o = ch*7 + ol;
    if (o >= NB*NU) return;
    const int bb = o / NU, uu = o % NU;
    const int nt_ = bb >> 4, bn = bb & 15;
    const float* wrow = lin_w + (size_t)uu*IN1_ + d*HID_;
    float sum = 0.f;
    for (int k = ln*25; k < ln*25 + 25; ++k) {
        const int kc = k >> 5, w5 = k & 31;
        const int l_ = ((w5>>3)<<4) | bn, i_ = w5 & 7;
        sum += bf2f(stageB[kc*1024 + nt_*512 + l_*8 + i_]) * wrow[k];
    }
#pragma unroll
    for (int off2 = 16; off2; off2 >>= 1) sum += __shfl_down(sum, off2, 32);
    if (ln == 0) logits[((size_t)d*T_LEN + tprev)*640 + o] = sum;
}

// ---------------- Layer 1: persistent, 2 x 100 blocks; fused x-GEMM + linear ----------------
__global__ __launch_bounds__(256, 1)
void lstm1_persist(const float* __restrict__ wih1, const float* __restrict__ whh1,
                   const float* __restrict__ bias, const float* __restrict__ lin_w,
                   const u16* __restrict__ h0f, u16* __restrict__ hB,
                   int* __restrict__ flags, float* __restrict__ logits)
{
    __shared__ __align__(16) u16 wihL[2*50*512];        // 100 KB w_ih1 A-frags
    __shared__ __align__(16) u16 stageB[25600];         // 51.2 KB (NOT aliased: logit reads)
    __shared__ __align__(16) float part[2048];          // 8 KB
    __shared__ u16 hpk[NB*8];
    const int tid = threadIdx.x;
    const int d = blockIdx.x / NCH1, ch = blockIdx.x % NCH1;
    const int w = tid >> 6, l = tid & 63;
    const int p = w & 1, hl = w >> 1;
    int* myflags = flags + d*NCH1*16;

    short8 wreg[25];
    {
        const int m = l & 15, g = p*2 + (m>>3), j = ch*8 + (m&7);
        const float* base = whh1 + ((size_t)(d*G4_ + g*HID_ + j))*HID_ + (l>>4)*8;
#pragma unroll
        for (int kc = 0; kc < 25; ++kc) {
            float4 f0 = *(const float4*)(base + kc*32);
            float4 f1 = *(const float4*)(base + kc*32 + 4);
            short8 v;
            v[0]=cvt_hl(f0.x,hl); v[1]=cvt_hl(f0.y,hl); v[2]=cvt_hl(f0.z,hl); v[3]=cvt_hl(f0.w,hl);
            v[4]=cvt_hl(f1.x,hl); v[5]=cvt_hl(f1.y,hl); v[6]=cvt_hl(f1.z,hl); v[7]=cvt_hl(f1.w,hl);
            wreg[kc] = v;
        }
    }
    for (int o = tid; o < 6400; o += 256) {
        int pp = o / 3200, r = o % 3200, kc = r >> 6, ll = r & 63;
        int m = ll & 15, g = pp*2 + (m>>3), jj = ch*8 + (m&7);
        const float* base = wih1 + ((size_t)(d*G4_ + g*HID_ + jj))*IN1_ + kc*32 + (ll>>4)*8;
        float4 f0 = *(const float4*)base;
        float4 f1 = *(const float4*)(base + 4);
        short8 v;
        v[0]=(short)f2bf(f0.x); v[1]=(short)f2bf(f0.y); v[2]=(short)f2bf(f0.z); v[3]=(short)f2bf(f0.w);
        v[4]=(short)f2bf(f1.x); v[5]=(short)f2bf(f1.y); v[6]=(short)f2bf(f1.z); v[7]=(short)f2bf(f1.w);
        *(short8*)&wihL[o*8] = v;
    }
    const int ju = tid >> 5, b = tid & 31;
    const int j = ch*8 + ju;
    const int nt = b >> 4, n = b & 15;
    float biasr[4];
#pragma unroll
    for (int g = 0; g < 4; ++g) biasr[g] = bias[d*G4_ + g*HID_ + j];
    float creg = 0.f;
    __syncthreads();

    for (int s = 0; s < T_LEN; ++s) {
        const int t = d ? (T_LEN-1-s) : s;
        const u64* hq64 = (const u64*)(hB + (size_t)((s&1)*2 + d)*25600);
        u64*      hnq  = (u64*)(hB + (size_t)(((s&1)^1)*2 + d)*25600);

        // x-part GEMM BEFORE the poll: depends only on h0f (previous dispatch)
        f32x4 acc0 = {0.f,0.f,0.f,0.f}, acc1 = {0.f,0.f,0.f,0.f};
        {
            const u16* xb = h0f + (size_t)t*51200;
#pragma unroll 5
            for (int kc = 0; kc < 25; ++kc) {
                const int idx = hl*25 + kc;
                short8 a  = *(const short8*)&wihL[(p*50 + idx)*512 + l*8];
                short8 b0 = *(const short8*)(xb + idx*1024 + l*8);
                short8 b1 = *(const short8*)(xb + idx*1024 + 512 + l*8);
                acc0 = mfma16(a, b0, acc0);
                acc1 = mfma16(a, b1, acc1);
            }
        }

        if (s > 0 && tid < NCH1)
            while (afload(myflags + tid*16) < s) __builtin_amdgcn_s_sleep(1);
        __syncthreads();

        {
            u64 tmp[25];
#pragma unroll
            for (int q = 0; q < 25; ++q) tmp[q] = aload(hq64 + tid + q*256);
#pragma unroll
            for (int q = 0; q < 25; ++q) ((u64*)stageB)[tid + q*256] = tmp[q];
        }
        __syncthreads();

#pragma unroll 5
        for (int kc = 0; kc < 25; ++kc) {
            short8 b0 = *(const short8*)(stageB + kc*1024 + l*8);
            short8 b1 = *(const short8*)(stageB + kc*1024 + 512 + l*8);
            acc0 = mfma16(wreg[kc], b0, acc0);
            acc1 = mfma16(wreg[kc], b1, acc1);
        }
        {
            const int mrow = (l>>4)*4, nn = l & 15;
#pragma unroll
            for (int r = 0; r < 4; ++r) {
                part[(((p*2+hl)*2 + 0)*16 + mrow + r)*16 + nn] = acc0[r];
                part[(((p*2+hl)*2 + 1)*16 + mrow + r)*16 + nn] = acc1[r];
            }
        }
        __syncthreads();

        float v[4];
#pragma unroll
        for (int g = 0; g < 4; ++g) {
            const int pp = g >> 1, m = (g & 1)*8 + ju;
            v[g] = part[(((pp*2+0)*2 + nt)*16 + m)*16 + n]
                 + part[(((pp*2+1)*2 + nt)*16 + m)*16 + n] + biasr[g];
        }
        float ig = 1.f/(1.f + expf(-v[0]));
        float fg = 1.f/(1.f + expf(-v[1]));
        float gg = tanhf(v[2]);
        float og = 1.f/(1.f + expf(-v[3]));
        creg = fg * creg + ig * gg;
        float hn = og * tanhf(creg);
        hpk[b*8 + ju] = f2bf(hn);
        __syncthreads();

        if (tid < 64) {
            const int bb = tid >> 1, half = tid & 1;
            const u16* hp = &hpk[bb*8 + half*4];
            u64 pk = (u64)hp[0] | ((u64)hp[1]<<16) | ((u64)hp[2]<<32) | ((u64)hp[3]<<48);
            const int ntb = bb >> 4, llb = ((ch&3)<<4) | (bb&15);
            astore(hnq + ((ch>>2)*2 + ntb)*128 + llb*2 + half, pk);
        }
        __syncthreads();                       // drain h stores
        if (tid == 0) afstore(myflags + ch*16, s+1);

        // distributed logit compute for t(s-1) from stageB (h of previous step);
        // post-flag: hides in the next poll window. Plain stores, zero contention.
        if (s > 0)
            logit_from_stage(stageB, lin_w, logits, d, ch,
                             d ? (T_LEN - s) : (s - 1), tid);
    }
    // final round: logits for t(T-1) — stage the last h and compute
    if (tid < NCH1)
        while (afload(myflags + tid*16) < T_LEN) __builtin_amdgcn_s_sleep(1);
    __syncthreads();
    {
        const u64* hq64 = (const u64*)(hB + (size_t)((T_LEN&1)*2 + d)*25600);
        u64 tmp[25];
#pragma unroll
        for (int q = 0; q < 25; ++q) tmp[q] = aload(hq64 + tid + q*256);
#pragma unroll
        for (int q = 0; q < 25; ++q) ((u64*)stageB)[tid + q*256] = tmp[q];
    }
    __syncthreads();
    logit_from_stage(stageB, lin_w, logits, d, ch, d ? 0 : (T_LEN - 1), tid);
}

// ---- sum dirs + lin_b -> softmax -> alphabet sin/cos mix; store (cosP, sinP) ----
__global__ __launch_bounds__(256)
void epilogue(const float* __restrict__ logits, const float* __restrict__ lin_b,
              const float* __restrict__ alphabet, float* __restrict__ cs)
{
    __shared__ float sa[NU*3], ca[NU*3], lb[NU];
    const int tid = threadIdx.x;
    if (tid < NU*3) { float al = alphabet[tid]; sa[tid] = sinf(al); ca[tid] = cosf(al); }
    if (tid < NU) lb[tid] = lin_b[tid];
    __syncthreads();
    const int row = blockIdx.x*256 + tid;   // t*NB + b
    if (row >= T_LEN*NB) return;
    const int t = row >> 5, b = row & 31;
    float lg[NU];
    float m = -1e30f;
#pragma unroll 4
    for (int u = 0; u < NU; ++u) {
        lg[u] = lb[u] + logits[(size_t)t*640 + b*NU + u]
                      + logits[((size_t)T_LEN + t)*640 + b*NU + u];
        m = fmaxf(m, lg[u]);
    }
    float ssum = 0.f;
#pragma unroll 4
    for (int u = 0; u < NU; ++u) { lg[u] = expf(lg[u] - m); ssum += lg[u]; }
    float inv = 1.f / ssum;
#pragma unroll
    for (int i = 0; i < 3; ++i) {
        float sv = 0.f, cv = 0.f;
#pragma unroll 4
        for (int u = 0; u < NU; ++u) {
            float sw = lg[u] * inv;
            sv += sw * sa[u*3 + i];
            cv += sw * ca[u*3 + i];
        }
        float rinv = rsqrtf(fmaxf(sv*sv + cv*cv, 1e-30f));
        *(float2*)(cs + ((size_t)row*3 + i)*2) = make_float2(cv*rinv, sv*rinv);
    }
}

// ---- sequential chain extension: one lane per molecule ----
__global__ __launch_bounds__(64)
void geometry(const float* __restrict__ cs, float* __restrict__ out)
{
    const int b = threadIdx.x;
    if (b >= NB) return;
    const float blen[3] = {1.329f, 1.459f, 1.525f};
    const float bang[3] = {2.034f, 2.119f, 1.937f};
    float sT[3], cT[3];
#pragma unroll
    for (int i = 0; i < 3; ++i) { sT[i] = sinf(bang[i]); cT[i] = cosf(bang[i]); }

    float Ax=0.f,Ay=0.f,Az=1.f, Bx=0.f,By=1.f,Bz=0.f, Cx=1.f,Cy=0.f,Cz=0.f;
    out[(0*NB + b)*3 + 0] = 0.f; out[(0*NB + b)*3 + 1] = 0.f; out[(0*NB + b)*3 + 2] = 1.f;
    out[(1*NB + b)*3 + 0] = 0.f; out[(1*NB + b)*3 + 1] = 1.f; out[(1*NB + b)*3 + 2] = 0.f;
    out[(2*NB + b)*3 + 0] = 1.f; out[(2*NB + b)*3 + 1] = 0.f; out[(2*NB + b)*3 + 2] = 0.f;

    for (int t = 1; t < T_LEN; ++t) {
        float2 pc[3];
#pragma unroll
        for (int i = 0; i < 3; ++i)
            pc[i] = *(const float2*)(cs + (((size_t)t*NB + b)*3 + i)*2);
#pragma unroll
        for (int i = 0; i < 3; ++i) {
            float R = blen[i];
            float d2x = -R*cT[i], d2y = R*pc[i].x*sT[i], d2z = R*pc[i].y*sT[i];
            float bcx = Cx-Bx, bcy = Cy-By, bcz = Cz-Bz;
            float inv = rsqrtf(bcx*bcx + bcy*bcy + bcz*bcz);
            bcx *= inv; bcy *= inv; bcz *= inv;
            float abx = Bx-Ax, aby = By-Ay, abz = Bz-Az;
            float nx = aby*bcz - abz*bcy;
            float ny = abz*bcx - abx*bcz;
            float nz = abx*bcy - aby*bcx;
            inv = rsqrtf(fmaxf(nx*nx + ny*ny + nz*nz, 1e-30f));
            nx *= inv; ny *= inv; nz *= inv;
            float mx = ny*bcz - nz*bcy;
            float my = nz*bcx - nx*bcz;
            float mz = nx*bcy - ny*bcx;
            float Dx = bcx*d2x + mx*d2y + nx*d2z + Cx;
            float Dy = bcy*d2x + my*d2y + ny*d2z + Cy;
            float Dz = bcz*d2x + mz*d2y + nz*d2z + Cz;
            Ax=Bx; Ay=By; Az=Bz; Bx=Cx; By=Cy; Bz=Cz; Cx=Dx; Cy=Dy; Cz=Dz;
            const int r = 3 + (t-1)*3 + i;
            out[((size_t)r*NB + b)*3 + 0] = Dx;
            out[((size_t)r*NB + b)*3 + 1] = Dy;
            out[((size_t)r*NB + b)*3 + 2] = Dz;
        }
    }
}

extern "C" void kernel_launch(void* const* d_in, const int* in_sizes, int n_in,
                              void* d_out, int out_size, void* d_ws, size_t ws_size,
                              hipStream_t stream)
{
    (void)in_sizes; (void)n_in; (void)out_size; (void)ws_size;
    const float* seq   = (const float*)d_in[0];
    const float* w_ih0 = (const float*)d_in[2];
    const float* w_hh0 = (const float*)d_in[3];
    const float* b0    = (const float*)d_in[4];
    const float* w_ih1 = (const float*)d_in[5];
    const float* w_hh1 = (const float*)d_in[6];
    const float* b1    = (const float*)d_in[7];
    const float* lin_w = (const float*)d_in[8];
    const float* lin_b = (const float*)d_in[9];
    const float* alpha = (const float*)d_in[10];

    // workspace (~55.7 MB)
    char* ws = (char*)d_ws;
    size_t off = 0;
    u16* h0f   = (u16*)(ws + off); off += 52428800ull;   // [t][kc50][nt2][lane][i] bf16
    u16* hB    = (u16*)(ws + off); off += 204800ull;     // 2 bufs x 2 dirs x 25600 bf16
    int* flagsL0 = (int*)(ws + off); off += 6400ull;     // [d][ch<50] x 64B
    int* flagsL1 = (int*)(ws + off); off += 12800ull;    // [d][ch<100] x 64B
    float* logits = (float*)(ws + off); off += 2621440ull; // [d][t][b*20+u] fp32
    float* cs = (float*)(ws + off); off += 393216ull;

    hipMemsetAsync(hB, 0, 204800 + 6400 + 12800, stream);   // hB + both flag arrays

    lstm0_persist<<<dim3(2*NCH0), dim3(256), 0, stream>>>(seq, w_ih0, w_hh0, b0, h0f, hB, flagsL0);

    hipMemsetAsync(hB, 0, 204800, stream);   // re-zero h state for layer 1
    lstm1_persist<<<dim3(2*NCH1), dim3(256), 0, stream>>>(w_ih1, w_hh1, b1, lin_w, h0f, hB,
                                                          flagsL1, logits);

    epilogue<<<dim3(64), dim3(256), 0, stream>>>(logits, lin_b, alpha, cs);
    geometry<<<dim3(1), dim3(64), 0, stream>>>(cs, (float*)d_out);
}

// Round 9
// 9443.880 us; speedup vs baseline: 1.1083x; 1.1083x over previous
//
#include <hip/hip_runtime.h>
#include <math.h>

#define T_LEN 512
#define NB    32
#define EMB_  41
#define IN0_  42
#define HID_  800
#define G4_   3200
#define IN1_  1600
#define NU    20
#define NCH   100   // blocks per direction

typedef unsigned short u16;
typedef unsigned int   u32;
typedef unsigned long long u64;
typedef __attribute__((ext_vector_type(8))) short short8;
typedef __attribute__((ext_vector_type(4))) float f32x4;

__device__ __forceinline__ float bf2f(u16 v) {
    union { u32 u; float f; } c; c.u = ((u32)v) << 16; return c.f;
}
__device__ __forceinline__ u16 f2bf(float f) {
    union { float f; u32 u; } c; c.f = f;
    u32 r = (c.u + 0x7fffu + ((c.u >> 16) & 1u)) >> 16;
    return (u16)r;
}
__device__ __forceinline__ short cvt_hl(float v, int hl) {
    u16 hi = f2bf(v);
    return hl ? (short)f2bf(v - bf2f(hi)) : (short)hi;
}
__device__ __forceinline__ f32x4 mfma16(short8 a, short8 b, f32x4 c) {
    return __builtin_amdgcn_mfma_f32_16x16x32_bf16(a, b, c, 0, 0, 0);
}
__device__ __forceinline__ u64 aload(const u64* p) {
    return __hip_atomic_load(p, __ATOMIC_RELAXED, __HIP_MEMORY_SCOPE_AGENT);
}
__device__ __forceinline__ void astore(u64* p, u64 v) {
    __hip_atomic_store(p, v, __ATOMIC_RELAXED, __HIP_MEMORY_SCOPE_AGENT);
}
__device__ __forceinline__ int afload(const int* p) {
    return __hip_atomic_load(p, __ATOMIC_RELAXED, __HIP_MEMORY_SCOPE_AGENT);
}
__device__ __forceinline__ void afstore(int* p, int v) {
    __hip_atomic_store(p, v, __ATOMIC_RELAXED, __HIP_MEMORY_SCOPE_AGENT);
}

// ---------------- Layer 0: persistent, 200 blocks x 256 threads (round-7 proven) ----------------
__global__ __launch_bounds__(256, 1)
void lstm0_persist(const float* __restrict__ seq, const float* __restrict__ wih0,
                   const float* __restrict__ whh0, const float* __restrict__ bias,
                   u16* __restrict__ h0f, u16* __restrict__ hB, int* __restrict__ flags)
{
    __shared__ __align__(16) float part[2048];          // 8 KB
    __shared__ __align__(16) u16 stageB[25600];         // 51.2 KB h-slab stage
    __shared__ __align__(16) float w0l[32*48];          // 6 KB
    __shared__ __align__(16) float xsl[32*48];          // 6 KB
    __shared__ u16 hpk[NB*8];
    const int tid = threadIdx.x;
    const int d = blockIdx.x / NCH, ch = blockIdx.x % NCH;
    const int w = tid >> 6, l = tid & 63;
    const int p = w & 1, hl = w >> 1;
    int* myflags = flags + d*NCH*16;

    short8 wreg[25];   // whh0 hi/lo A-frags, register-resident
    {
        const int m = l & 15, g = p*2 + (m>>3), j = ch*8 + (m&7);
        const float* base = whh0 + ((size_t)(d*G4_ + g*HID_ + j))*HID_ + (l>>4)*8;
#pragma unroll
        for (int kc = 0; kc < 25; ++kc) {
            float4 f0 = *(const float4*)(base + kc*32);
            float4 f1 = *(const float4*)(base + kc*32 + 4);
            short8 v;
            v[0]=cvt_hl(f0.x,hl); v[1]=cvt_hl(f0.y,hl); v[2]=cvt_hl(f0.z,hl); v[3]=cvt_hl(f0.w,hl);
            v[4]=cvt_hl(f1.x,hl); v[5]=cvt_hl(f1.y,hl); v[6]=cvt_hl(f1.z,hl); v[7]=cvt_hl(f1.w,hl);
            wreg[kc] = v;
        }
    }
    for (int idx = tid; idx < 32*EMB_; idx += 256) {
        int r = idx / EMB_, k = idx % EMB_;
        int ju_ = r >> 2, g = r & 3;
        w0l[r*48 + k] = wih0[((size_t)(d*G4_ + g*HID_ + ch*8 + ju_))*IN0_ + k];
    }
    const int ju = tid >> 5, b = tid & 31;
    const int j = ch*8 + ju;
    const int nt = b >> 4, n = b & 15;
    float biasr[4], wpos[4];
#pragma unroll
    for (int g = 0; g < 4; ++g) {
        biasr[g] = bias[d*G4_ + g*HID_ + j];
        wpos[g]  = wih0[((size_t)(d*G4_ + g*HID_ + j))*IN0_ + EMB_];
    }
    float creg = 0.f;
    __syncthreads();

    for (int s = 0; s < T_LEN; ++s) {
        const int t = d ? (T_LEN-1-s) : s;
        const u64* hq64 = (const u64*)(hB + (size_t)((s&1)*2 + d)*25600);
        u64*      hnq  = (u64*)(hB + (size_t)(((s&1)^1)*2 + d)*25600);

        // h-independent work BEFORE the poll (overlaps peers' flag propagation)
        for (int idx = tid; idx < 32*EMB_; idx += 256)
            xsl[(idx/EMB_)*48 + idx%EMB_] = seq[(size_t)t*(NB*EMB_) + idx];

        if (s > 0 && tid < NCH)
            while (afload(myflags + tid*16) < s) __builtin_amdgcn_s_sleep(1);
        __syncthreads();

        {   // stage the 51.2 KB B-slab once per block
            u64 tmp[25];
#pragma unroll
            for (int q = 0; q < 25; ++q) tmp[q] = aload(hq64 + tid + q*256);
#pragma unroll
            for (int q = 0; q < 25; ++q) ((u64*)stageB)[tid + q*256] = tmp[q];
        }
        __syncthreads();

        f32x4 acc0 = {0.f,0.f,0.f,0.f}, acc1 = {0.f,0.f,0.f,0.f};
#pragma unroll 5
        for (int kc = 0; kc < 25; ++kc) {
            short8 b0 = *(const short8*)(stageB + kc*1024 + l*8);
            short8 b1 = *(const short8*)(stageB + kc*1024 + 512 + l*8);
            acc0 = mfma16(wreg[kc], b0, acc0);
            acc1 = mfma16(wreg[kc], b1, acc1);
        }
        {
            const int mrow = (l>>4)*4, nn = l & 15;
#pragma unroll
            for (int r = 0; r < 4; ++r) {
                part[(((p*2+hl)*2 + 0)*16 + mrow + r)*16 + nn] = acc0[r];
                part[(((p*2+hl)*2 + 1)*16 + mrow + r)*16 + nn] = acc1[r];
            }
        }
        __syncthreads();

        float dot0 = 0.f, dot1 = 0.f, dot2 = 0.f, dot3 = 0.f;
        {
            const float* wr = &w0l[ju*4*48];
            const float* xr = &xsl[b*48];
#pragma unroll
            for (int k4 = 0; k4 < 40; k4 += 4) {
                float4 xk = *(const float4*)(xr + k4);
                float4 w0 = *(const float4*)(wr + 0*48 + k4);
                float4 w1 = *(const float4*)(wr + 1*48 + k4);
                float4 w2 = *(const float4*)(wr + 2*48 + k4);
                float4 w3 = *(const float4*)(wr + 3*48 + k4);
                dot0 += w0.x*xk.x + w0.y*xk.y + w0.z*xk.z + w0.w*xk.w;
                dot1 += w1.x*xk.x + w1.y*xk.y + w1.z*xk.z + w1.w*xk.w;
                dot2 += w2.x*xk.x + w2.y*xk.y + w2.z*xk.z + w2.w*xk.w;
                dot3 += w3.x*xk.x + w3.y*xk.y + w3.z*xk.z + w3.w*xk.w;
            }
            float xk = xr[40];
            dot0 += wr[0*48+40]*xk; dot1 += wr[1*48+40]*xk;
            dot2 += wr[2*48+40]*xk; dot3 += wr[3*48+40]*xk;
        }
        float v[4] = {dot0, dot1, dot2, dot3};
#pragma unroll
        for (int g = 0; g < 4; ++g) {
            const int pp = g >> 1, m = (g & 1)*8 + ju;
            v[g] += part[(((pp*2+0)*2 + nt)*16 + m)*16 + n]
                  + part[(((pp*2+1)*2 + nt)*16 + m)*16 + n]
                  + biasr[g] + (float)t * wpos[g];
        }
        float ig = 1.f/(1.f + expf(-v[0]));
        float fg = 1.f/(1.f + expf(-v[1]));
        float gg = tanhf(v[2]);
        float og = 1.f/(1.f + expf(-v[3]));
        creg = fg * creg + ig * gg;
        hpk[b*8 + ju] = f2bf(og * tanhf(creg));
        __syncthreads();

        u64 pk = 0; int xoff = 0;
        if (tid < 64) {
            const int bb = tid >> 1, half = tid & 1;
            const u16* hp = &hpk[bb*8 + half*4];
            pk = (u64)hp[0] | ((u64)hp[1]<<16) | ((u64)hp[2]<<32) | ((u64)hp[3]<<48);
            const int ntb = bb >> 4, llb = ((ch&3)<<4) | (bb&15);
            astore(hnq + ((ch>>2)*2 + ntb)*128 + llb*2 + half, pk);    // next-step h
            xoff = ((d*25 + (ch>>2))*2 + ntb)*128 + llb*2 + half;
        }
        __syncthreads();                       // drains vmcnt: hB stores at coherence point
        if (tid == 0) afstore(myflags + ch*16, s+1);
        if (tid < 64)                          // cross-dispatch store AFTER the flag
            ((u64*)(h0f + (size_t)t*51200))[xoff] = pk;
    }
}

// ---------------- Layer 1: persistent; fused x-GEMM + distributed final linear ----------------
// Logits: block ch owns outputs o = ch*7+ol (ol<7, o<640). Thread (ol,ln) handles
// k = ln + 32*i (stride-32: <=2-way LDS bank aliasing, free) with its 25 lin_w
// values preloaded in registers. Plain stores, zero contention, post-flag.
__global__ __launch_bounds__(256, 1)
void lstm1_persist(const float* __restrict__ wih1, const float* __restrict__ whh1,
                   const float* __restrict__ bias, const float* __restrict__ lin_w,
                   const u16* __restrict__ h0f, u16* __restrict__ hB,
                   int* __restrict__ flags, float* __restrict__ logits)
{
    __shared__ __align__(16) u16 wihL[2*50*512];        // 100 KB w_ih1 A-frags
    __shared__ __align__(16) u16 stageB[25600];         // 51.2 KB (alive into logit compute)
    __shared__ __align__(16) float part[2048];          // 8 KB (separate: no alias sync)
    __shared__ u16 hpk[NB*8];
    const int tid = threadIdx.x;
    const int d = blockIdx.x / NCH, ch = blockIdx.x % NCH;
    const int w = tid >> 6, l = tid & 63;
    const int p = w & 1, hl = w >> 1;
    int* myflags = flags + d*NCH*16;

    short8 wreg[25];
    {
        const int m = l & 15, g = p*2 + (m>>3), j = ch*8 + (m&7);
        const float* base = whh1 + ((size_t)(d*G4_ + g*HID_ + j))*HID_ + (l>>4)*8;
#pragma unroll
        for (int kc = 0; kc < 25; ++kc) {
            float4 f0 = *(const float4*)(base + kc*32);
            float4 f1 = *(const float4*)(base + kc*32 + 4);
            short8 v;
            v[0]=cvt_hl(f0.x,hl); v[1]=cvt_hl(f0.y,hl); v[2]=cvt_hl(f0.z,hl); v[3]=cvt_hl(f0.w,hl);
            v[4]=cvt_hl(f1.x,hl); v[5]=cvt_hl(f1.y,hl); v[6]=cvt_hl(f1.z,hl); v[7]=cvt_hl(f1.w,hl);
            wreg[kc] = v;
        }
    }
    for (int o = tid; o < 6400; o += 256) {
        int pp = o / 3200, r = o % 3200, kc = r >> 6, ll = r & 63;
        int m = ll & 15, g = pp*2 + (m>>3), jj = ch*8 + (m&7);
        const float* base = wih1 + ((size_t)(d*G4_ + g*HID_ + jj))*IN1_ + kc*32 + (ll>>4)*8;
        float4 f0 = *(const float4*)base;
        float4 f1 = *(const float4*)(base + 4);
        short8 v;
        v[0]=(short)f2bf(f0.x); v[1]=(short)f2bf(f0.y); v[2]=(short)f2bf(f0.z); v[3]=(short)f2bf(f0.w);
        v[4]=(short)f2bf(f1.x); v[5]=(short)f2bf(f1.y); v[6]=(short)f2bf(f1.z); v[7]=(short)f2bf(f1.w);
        *(short8*)&wihL[o*8] = v;
    }
    // logit-owner constants + register-resident lin_w (step-invariant)
    const int ol = tid >> 5, ln = tid & 31;
    const int lo = ch*7 + ol;
    const bool lown = (ol < 7) && (lo < NB*NU);
    int lofs = 0;
    float wlin[25];
    if (lown) {
        const int bb = lo / NU, uu = lo % NU;
        lofs = (bb >> 4)*512 + ((((ln >> 3) << 4) | (bb & 15)))*8 + (ln & 7);
        const float* wrow = lin_w + (size_t)uu*IN1_ + d*HID_ + ln;
#pragma unroll
        for (int i = 0; i < 25; ++i) wlin[i] = wrow[i*32];
    }
    const int ju = tid >> 5, b = tid & 31;
    const int j = ch*8 + ju;
    const int nt = b >> 4, n = b & 15;
    float biasr[4];
#pragma unroll
    for (int g = 0; g < 4; ++g) biasr[g] = bias[d*G4_ + g*HID_ + j];
    float creg = 0.f;
    __syncthreads();

    for (int s = 0; s < T_LEN; ++s) {
        const int t = d ? (T_LEN-1-s) : s;
        const u64* hq64 = (const u64*)(hB + (size_t)((s&1)*2 + d)*25600);
        u64*      hnq  = (u64*)(hB + (size_t)(((s&1)^1)*2 + d)*25600);

        // x-part GEMM BEFORE the poll: depends only on h0f (previous dispatch)
        f32x4 acc0 = {0.f,0.f,0.f,0.f}, acc1 = {0.f,0.f,0.f,0.f};
        {
            const u16* xb = h0f + (size_t)t*51200;
#pragma unroll 5
            for (int kc = 0; kc < 25; ++kc) {
                const int idx = hl*25 + kc;
                short8 a  = *(const short8*)&wihL[(p*50 + idx)*512 + l*8];
                short8 b0 = *(const short8*)(xb + idx*1024 + l*8);
                short8 b1 = *(const short8*)(xb + idx*1024 + 512 + l*8);
                acc0 = mfma16(a, b0, acc0);
                acc1 = mfma16(a, b1, acc1);
            }
        }

        if (s > 0 && tid < NCH)
            while (afload(myflags + tid*16) < s) __builtin_amdgcn_s_sleep(1);
        __syncthreads();

        {
            u64 tmp[25];
#pragma unroll
            for (int q = 0; q < 25; ++q) tmp[q] = aload(hq64 + tid + q*256);
#pragma unroll
            for (int q = 0; q < 25; ++q) ((u64*)stageB)[tid + q*256] = tmp[q];
        }
        __syncthreads();

#pragma unroll 5
        for (int kc = 0; kc < 25; ++kc) {
            short8 b0 = *(const short8*)(stageB + kc*1024 + l*8);
            short8 b1 = *(const short8*)(stageB + kc*1024 + 512 + l*8);
            acc0 = mfma16(wreg[kc], b0, acc0);
            acc1 = mfma16(wreg[kc], b1, acc1);
        }
        {
            const int mrow = (l>>4)*4, nn = l & 15;
#pragma unroll
            for (int r = 0; r < 4; ++r) {
                part[(((p*2+hl)*2 + 0)*16 + mrow + r)*16 + nn] = acc0[r];
                part[(((p*2+hl)*2 + 1)*16 + mrow + r)*16 + nn] = acc1[r];
            }
        }
        __syncthreads();

        float v[4];
#pragma unroll
        for (int g = 0; g < 4; ++g) {
            const int pp = g >> 1, m = (g & 1)*8 + ju;
            v[g] = part[(((pp*2+0)*2 + nt)*16 + m)*16 + n]
                 + part[(((pp*2+1)*2 + nt)*16 + m)*16 + n] + biasr[g];
        }
        float ig = 1.f/(1.f + expf(-v[0]));
        float fg = 1.f/(1.f + expf(-v[1]));
        float gg = tanhf(v[2]);
        float og = 1.f/(1.f + expf(-v[3]));
        creg = fg * creg + ig * gg;
        float hn = og * tanhf(creg);
        hpk[b*8 + ju] = f2bf(hn);
        __syncthreads();

        if (tid < 64) {
            const int bb = tid >> 1, half = tid & 1;
            const u16* hp = &hpk[bb*8 + half*4];
            u64 pk = (u64)hp[0] | ((u64)hp[1]<<16) | ((u64)hp[2]<<32) | ((u64)hp[3]<<48);
            const int ntb = bb >> 4, llb = ((ch&3)<<4) | (bb&15);
            astore(hnq + ((ch>>2)*2 + ntb)*128 + llb*2 + half, pk);
        }
        __syncthreads();                       // drain h stores
        if (tid == 0) afstore(myflags + ch*16, s+1);

        // distributed logits for the h staged THIS step (time tprev), post-flag.
        // stageB stays valid until the next step's staging (after poll+sync).
        if (s > 0 && lown) {
            float sum = 0.f;
#pragma unroll
            for (int i = 0; i < 25; ++i)
                sum += bf2f(stageB[i*1024 + lofs]) * wlin[i];
#pragma unroll
            for (int off2 = 16; off2; off2 >>= 1) sum += __shfl_down(sum, off2, 32);
            if (ln == 0) {
                const int tprev = d ? (T_LEN - s) : (s - 1);
                logits[((size_t)d*T_LEN + tprev)*640 + lo] = sum;
            }
        }
    }
    // tail: logits for the final h (staged in buffer (T_LEN&1)*2+d = buffer 0)
    if (tid < NCH)
        while (afload(myflags + tid*16) < T_LEN) __builtin_amdgcn_s_sleep(1);
    __syncthreads();
    {
        const u64* hq64 = (const u64*)(hB + (size_t)((T_LEN&1)*2 + d)*25600);
        u64 tmp[25];
#pragma unroll
        for (int q = 0; q < 25; ++q) tmp[q] = aload(hq64 + tid + q*256);
#pragma unroll
        for (int q = 0; q < 25; ++q) ((u64*)stageB)[tid + q*256] = tmp[q];
    }
    __syncthreads();
    if (lown) {
        float sum = 0.f;
#pragma unroll
        for (int i = 0; i < 25; ++i)
            sum += bf2f(stageB[i*1024 + lofs]) * wlin[i];
#pragma unroll
        for (int off2 = 16; off2; off2 >>= 1) sum += __shfl_down(sum, off2, 32);
        if (ln == 0) {
            const int tprev = d ? 0 : (T_LEN - 1);
            logits[((size_t)d*T_LEN + tprev)*640 + lo] = sum;
        }
    }
}

// ---- sum dirs + lin_b -> softmax -> alphabet sin/cos mix; store (cosP, sinP) ----
__global__ __launch_bounds__(256)
void epilogue(const float* __restrict__ logits, const float* __restrict__ lin_b,
              const float* __restrict__ alphabet, float* __restrict__ cs)
{
    __shared__ float sa[NU*3], ca[NU*3], lb[NU];
    const int tid = threadIdx.x;
    if (tid < NU*3) { float al = alphabet[tid]; sa[tid] = sinf(al); ca[tid] = cosf(al); }
    if (tid < NU) lb[tid] = lin_b[tid];
    __syncthreads();
    const int row = blockIdx.x*256 + tid;   // t*NB + b
    if (row >= T_LEN*NB) return;
    const int t = row >> 5, b = row & 31;
    float lg[NU];
    float m = -1e30f;
#pragma unroll 4
    for (int u = 0; u < NU; ++u) {
        lg[u] = lb[u] + logits[(size_t)t*640 + b*NU + u]
                      + logits[((size_t)T_LEN + t)*640 + b*NU + u];
        m = fmaxf(m, lg[u]);
    }
    float ssum = 0.f;
#pragma unroll 4
    for (int u = 0; u < NU; ++u) { lg[u] = expf(lg[u] - m); ssum += lg[u]; }
    float inv = 1.f / ssum;
#pragma unroll
    for (int i = 0; i < 3; ++i) {
        float sv = 0.f, cv = 0.f;
#pragma unroll 4
        for (int u = 0; u < NU; ++u) {
            float sw = lg[u] * inv;
            sv += sw * sa[u*3 + i];
            cv += sw * ca[u*3 + i];
        }
        float rinv = rsqrtf(fmaxf(sv*sv + cv*cv, 1e-30f));
        *(float2*)(cs + ((size_t)row*3 + i)*2) = make_float2(cv*rinv, sv*rinv);
    }
}

// ---- sequential chain extension: one lane per molecule ----
__global__ __launch_bounds__(64)
void geometry(const float* __restrict__ cs, float* __restrict__ out)
{
    const int b = threadIdx.x;
    if (b >= NB) return;
    const float blen[3] = {1.329f, 1.459f, 1.525f};
    const float bang[3] = {2.034f, 2.119f, 1.937f};
    float sT[3], cT[3];
#pragma unroll
    for (int i = 0; i < 3; ++i) { sT[i] = sinf(bang[i]); cT[i] = cosf(bang[i]); }

    float Ax=0.f,Ay=0.f,Az=1.f, Bx=0.f,By=1.f,Bz=0.f, Cx=1.f,Cy=0.f,Cz=0.f;
    out[(0*NB + b)*3 + 0] = 0.f; out[(0*NB + b)*3 + 1] = 0.f; out[(0*NB + b)*3 + 2] = 1.f;
    out[(1*NB + b)*3 + 0] = 0.f; out[(1*NB + b)*3 + 1] = 1.f; out[(1*NB + b)*3 + 2] = 0.f;
    out[(2*NB + b)*3 + 0] = 1.f; out[(2*NB + b)*3 + 1] = 0.f; out[(2*NB + b)*3 + 2] = 0.f;

    for (int t = 1; t < T_LEN; ++t) {
        float2 pc[3];
#pragma unroll
        for (int i = 0; i < 3; ++i)
            pc[i] = *(const float2*)(cs + (((size_t)t*NB + b)*3 + i)*2);
#pragma unroll
        for (int i = 0; i < 3; ++i) {
            float R = blen[i];
            float d2x = -R*cT[i], d2y = R*pc[i].x*sT[i], d2z = R*pc[i].y*sT[i];
            float bcx = Cx-Bx, bcy = Cy-By, bcz = Cz-Bz;
            float inv = rsqrtf(bcx*bcx + bcy*bcy + bcz*bcz);
            bcx *= inv; bcy *= inv; bcz *= inv;
            float abx = Bx-Ax, aby = By-Ay, abz = Bz-Az;
            float nx = aby*bcz - abz*bcy;
            float ny = abz*bcx - abx*bcz;
            float nz = abx*bcy - aby*bcx;
            inv = rsqrtf(fmaxf(nx*nx + ny*ny + nz*nz, 1e-30f));
            nx *= inv; ny *= inv; nz *= inv;
            float mx = ny*bcz - nz*bcy;
            float my = nz*bcx - nx*bcz;
            float mz = nx*bcy - ny*bcx;
            float Dx = bcx*d2x + mx*d2y + nx*d2z + Cx;
            float Dy = bcy*d2x + my*d2y + ny*d2z + Cy;
            float Dz = bcz*d2x + mz*d2y + nz*d2z + Cz;
            Ax=Bx; Ay=By; Az=Bz; Bx=Cx; By=Cy; Bz=Cz; Cx=Dx; Cy=Dy; Cz=Dz;
            const int r = 3 + (t-1)*3 + i;
            out[((size_t)r*NB + b)*3 + 0] = Dx;
            out[((size_t)r*NB + b)*3 + 1] = Dy;
            out[((size_t)r*NB + b)*3 + 2] = Dz;
        }
    }
}

extern "C" void kernel_launch(void* const* d_in, const int* in_sizes, int n_in,
                              void* d_out, int out_size, void* d_ws, size_t ws_size,
                              hipStream_t stream)
{
    (void)in_sizes; (void)n_in; (void)out_size; (void)ws_size;
    const float* seq   = (const float*)d_in[0];
    const float* w_ih0 = (const float*)d_in[2];
    const float* w_hh0 = (const float*)d_in[3];
    const float* b0    = (const float*)d_in[4];
    const float* w_ih1 = (const float*)d_in[5];
    const float* w_hh1 = (const float*)d_in[6];
    const float* b1    = (const float*)d_in[7];
    const float* lin_w = (const float*)d_in[8];
    const float* lin_b = (const float*)d_in[9];
    const float* alpha = (const float*)d_in[10];

    // workspace (~55.7 MB)
    char* ws = (char*)d_ws;
    size_t off = 0;
    u16* h0f   = (u16*)(ws + off); off += 52428800ull;   // [t][kc50][nt2][lane][i] bf16
    u16* hB    = (u16*)(ws + off); off += 204800ull;     // 2 bufs x 2 dirs x 25600 bf16
    int* flagsL0 = (int*)(ws + off); off += 12800ull;    // [d][ch] x 64B
    int* flagsL1 = (int*)(ws + off); off += 12800ull;
    float* logits = (float*)(ws + off); off += 2621440ull; // [d][t][b*20+u] fp32
    float* cs = (float*)(ws + off); off += 393216ull;

    hipMemsetAsync(hB, 0, 204800 + 12800 + 12800, stream);   // hB + both flag arrays

    lstm0_persist<<<dim3(2*NCH), dim3(256), 0, stream>>>(seq, w_ih0, w_hh0, b0, h0f, hB, flagsL0);

    hipMemsetAsync(hB, 0, 204800, stream);   // re-zero h state for layer 1
    lstm1_persist<<<dim3(2*NCH), dim3(256), 0, stream>>>(w_ih1, w_hh1, b1, lin_w, h0f, hB,
                                                         flagsL1, logits);

    epilogue<<<dim3(64), dim3(256), 0, stream>>>(logits, lin_b, alpha, cs);
    geometry<<<dim3(1), dim3(64), 0, stream>>>(cs, (float*)d_out);
}